// Round 14
// baseline (374.664 us; speedup 1.0000x reference)
//
#include <hip/hip_runtime.h>
#include <math.h>

// ---------------------------------------------------------------------------
// CoTracker correlation-embedding pipeline, bf16 MFMA, HWC-padded fmaps.
// Round 13: gemm1 restructured to 128x384 full-N tile (512 thr, 8 waves,
// wave tile 64x96) -> 0.42 ds_reads/MFMA (was 0.5), 1 barrier-pair per
// K-step (was 3 blocks' worth), A staged once. Everything else = R12.
// Inputs: 0:fmaps0 1:track0 2:fmaps1 3:track1 4:fmaps2 5:track2 6:fmaps3
//         7:track3 8:coords 9:vis 10:conf 11:w1 12:b1 13:w2 14:b2 15:time_emb
// Output: (1,N,8,1110) f32.
// ---------------------------------------------------------------------------

#define SN 8
#define NN 1024
#define CC 128
#define K1P2 2752   // 343*8 = 2744 data + 8 pad (86 K-steps of 32)
#define H1 384
#define H2 256
#define DOUT 1110

typedef short bf16x8 __attribute__((ext_vector_type(8)));
typedef short s16x4 __attribute__((ext_vector_type(4)));
typedef float f32x4 __attribute__((ext_vector_type(4)));

__device__ inline unsigned short f2b(float x) {  // RTNE f32 -> bf16
    union { float f; unsigned u; } v; v.f = x;
    unsigned r = v.u + 0x7FFFu + ((v.u >> 16) & 1u);
    return (unsigned short)(r >> 16);
}
__device__ inline float b2f(unsigned short u) {
    union { unsigned u; float f; } v; v.u = (unsigned)u << 16; return v.f;
}
__device__ inline void gll16(const void* g, void* l) {
    __builtin_amdgcn_global_load_lds(
        (const __attribute__((address_space(1))) void*)g,
        (__attribute__((address_space(3))) void*)l, 16, 0, 0);
}
// XOR-swizzled LDS index (shorts) for [rows][128] bf16 MFMA operand tiles.
__device__ inline int swz(int row, int g) {
    return row * 128 + ((g ^ (row & 7)) << 3);
}

// ---------------------------------------------------------------------------
// fmap fp32 (S,C,H,W) -> bf16 HWC padded (S, H+8, W+8, C), border replicate.
// ---------------------------------------------------------------------------
__global__ __launch_bounds__(256) void conv_fmap_kernel(
    const float* __restrict__ in, unsigned short* __restrict__ outp,
    int H, int W)
{
    const int Hp = H + 8, Wp = W + 8;
    const int s = blockIdx.x / Hp, yp = blockIdx.x % Hp;
    const int y = min(max(yp - 4, 0), H - 1);
    const float* src = in + (size_t)s * CC * H * W + (size_t)y * W;
    unsigned short* dst = outp + ((size_t)s * Hp + yp) * Wp * CC;
    for (int idx = threadIdx.x; idx < Wp * CC; idx += 256) {
        int xp = idx >> 7, c = idx & 127;
        int x = min(max(xp - 4, 0), W - 1);
        dst[idx] = f2b(src[(size_t)c * H * W + x]);
    }
}

// ---------------------------------------------------------------------------
// Kernel A (fused over levels): block -> (g = blk>>10, n = blk&1023).
// 2-deep patch pipeline (bufB aliases trk after register-hoist). Per s:
// [counted vmcnt + bar] MFMA pc -> pcL bf16 [lgkm bar] issue patch(sl+2)
// -> bilinear (b64 taps) -> permuted-K vol (dwordx4 stores).
// LDS 50.6KB -> 3 blocks/CU.
// ---------------------------------------------------------------------------
__global__ __launch_bounds__(256, 3) void sample_vol_kernel(
    const unsigned short* __restrict__ fq0, const unsigned short* __restrict__ fq1,
    const unsigned short* __restrict__ fq2, const unsigned short* __restrict__ fq3,
    const float* __restrict__ tk0, const float* __restrict__ tk1,
    const float* __restrict__ tk2, const float* __restrict__ tk3,
    const float* __restrict__ coords,        // (8, N, 2) f32
    unsigned short* __restrict__ vol,        // (n_lv*8*N, 2752) bf16 permuted-K
    int lv0)
{
    __shared__ __align__(16) unsigned short bufA[80 * 128]; // 20 KB
    __shared__ __align__(16) unsigned short bufB[80 * 128]; // 20 KB (trk alias)
    __shared__ __align__(16) unsigned short pcL[80 * 68];   // 10.6 KB
    const int n = blockIdx.x & 1023, g = blockIdx.x >> 10;
    const int lvl = lv0 + g;
    const unsigned short* fpad = (lvl == 0) ? fq0 : (lvl == 1) ? fq1
                               : (lvl == 2) ? fq2 : fq3;
    const float* track = (lvl == 0) ? tk0 : (lvl == 1) ? tk1
                       : (lvl == 2) ? tk2 : tk3;
    const int Wp = (128 >> lvl) + 8;
    const int t = threadIdx.x;
    const int lane = t & 63, wv = t >> 6;
    const int rsub = lane & 15, kq = lane >> 4;
    const float inv = 1.0f / (float)(1 << lvl);
    const size_t plane = (size_t)((96 >> lvl) + 8) * Wp * CC;

    int poff[5], ldso[5];
    #pragma unroll
    for (int i = 0; i < 5; ++i) {
        int task64 = wv * 5 + i;
        int point = task64 * 4 + (lane >> 4);  // patch row 0..79
        int v = point / 10, xs = point - v * 10;
        int j = (lane & 15) ^ (point & 7);
        poff[i] = (v * Wp + xs) * CC + j * 8;
        ldso[i] = task64 * 512;
    }

    float cxa[SN], cya[SN];
    int fxa[SN], fya[SN], ea[SN];
    #pragma unroll
    for (int s = 0; s < SN; ++s) {
        float2 c2 = *(const float2*)&coords[((size_t)s * NN + n) * 2];
        cxa[s] = c2.x * inv; cya[s] = c2.y * inv;
        fxa[s] = (int)floorf(cxa[s]);
        fya[s] = (int)floorf(cya[s]);
        ea[s] = (fxa[s] - 3) & ~1;
    }

    int p0b[2], ij0a[2], tau8[2]; bool vld[2];
    #pragma unroll
    for (int rep = 0; rep < 2; ++rep) {
        int tau = t + rep * 256;
        vld[rep] = (tau < 343);
        int tt = vld[rep] ? tau : 0;
        int ab = tt / 7, blk = tt - 7 * ab;
        int a = ab / 7, b = ab - 7 * a;
        p0b[rep] = b * 10 + a;
        ij0a[rep] = blk * 8;
        tau8[rep] = tt * 8;
    }

    // patch s=0 -> bufA
    {
        const unsigned short* base =
            fpad + ((fya[0] + 1) * Wp + (ea[0] + 4)) * CC;
        #pragma unroll
        for (int i = 0; i < 5; ++i) gll16(base + poff[i], &bufA[ldso[i]]);
    }
    // track[n] -> bufB (trk layout, swizzled), once
    for (int task = t; task < 49 * 16; task += 256) {
        int row = task >> 4, gg = task & 15;
        const float* srcp = &track[((size_t)row * NN + n) * CC + gg * 8];
        float4 f0 = *(const float4*)srcp;
        float4 f1 = *(const float4*)(srcp + 4);
        bf16x8 v8;
        v8[0] = f2b(f0.x); v8[1] = f2b(f0.y); v8[2] = f2b(f0.z); v8[3] = f2b(f0.w);
        v8[4] = f2b(f1.x); v8[5] = f2b(f1.y); v8[6] = f2b(f1.z); v8[7] = f2b(f1.w);
        *(bf16x8*)&bufB[swz(row, gg)] = v8;
    }
    {
        unsigned* T32 = (unsigned*)bufB;
        for (int i = t; i < 15 * 64; i += 256) T32[49 * 64 + i] = 0;
    }
    asm volatile("s_waitcnt lgkmcnt(0)" ::: "memory");
    __builtin_amdgcn_sched_barrier(0);
    __builtin_amdgcn_s_barrier();
    bf16x8 tf[4];
    #pragma unroll
    for (int kk = 0; kk < 4; ++kk)
        tf[kk] = *(const bf16x8*)&bufB[swz(wv * 16 + rsub, kk * 4 + kq)];
    asm volatile("s_waitcnt lgkmcnt(0)" ::: "memory");
    __builtin_amdgcn_sched_barrier(0);
    __builtin_amdgcn_s_barrier();
    __builtin_amdgcn_sched_barrier(0);
    // patch s=1 -> bufB (now free)
    {
        const unsigned short* base =
            fpad + plane + ((fya[1] + 1) * Wp + (ea[1] + 4)) * CC;
        #pragma unroll
        for (int i = 0; i < 5; ++i) gll16(base + poff[i], &bufB[ldso[i]]);
    }

    #pragma unroll
    for (int sl = 0; sl < SN; ++sl) {
        unsigned short* pbuf = (sl & 1) ? bufB : bufA;
        const float wx = cxa[sl] - (float)fxa[sl], wy = cya[sl] - (float)fya[sl];
        const float w00 = (1.f - wx) * (1.f - wy), w10 = wx * (1.f - wy);
        const float w01 = (1.f - wx) * wy,         w11 = wx * wy;
        const int off = fxa[sl] - 3 - ea[sl];

        if (sl == 0) {
            asm volatile("s_waitcnt vmcnt(5) lgkmcnt(0)" ::: "memory");
        } else if (sl == 1) {
            if (wv < 2) asm volatile("s_waitcnt vmcnt(7) lgkmcnt(0)" ::: "memory");
            else        asm volatile("s_waitcnt vmcnt(6) lgkmcnt(0)" ::: "memory");
        } else if (sl == SN - 1) {
            if (wv < 2) asm volatile("s_waitcnt vmcnt(4) lgkmcnt(0)" ::: "memory");
            else        asm volatile("s_waitcnt vmcnt(2) lgkmcnt(0)" ::: "memory");
        } else {
            if (wv < 2) asm volatile("s_waitcnt vmcnt(9) lgkmcnt(0)" ::: "memory");
            else        asm volatile("s_waitcnt vmcnt(7) lgkmcnt(0)" ::: "memory");
        }
        __builtin_amdgcn_sched_barrier(0);
        __builtin_amdgcn_s_barrier();
        __builtin_amdgcn_sched_barrier(0);

        // ---- MFMA: pc[80][64] = patch(80x128) . trk(64x128)^T -> pcL bf16 --
        {
            f32x4 acc[5] = {};
            __builtin_amdgcn_s_setprio(1);
            #pragma unroll
            for (int kk = 0; kk < 4; ++kk) {
                int gg = kk * 4 + kq;
                #pragma unroll
                for (int ti = 0; ti < 5; ++ti) {
                    bf16x8 a = *(const bf16x8*)&pbuf[swz(ti * 16 + rsub, gg)];
                    acc[ti] = __builtin_amdgcn_mfma_f32_16x16x32_bf16(a, tf[kk], acc[ti], 0, 0, 0);
                }
            }
            __builtin_amdgcn_s_setprio(0);
            const int col = wv * 16 + rsub;
            #pragma unroll
            for (int ti = 0; ti < 5; ++ti)
                #pragma unroll
                for (int r = 0; r < 4; ++r)
                    pcL[(ti * 16 + kq * 4 + r) * 68 + col] = f2b(acc[ti][r]);
        }
        asm volatile("s_waitcnt lgkmcnt(0)" ::: "memory");
        __builtin_amdgcn_s_barrier();
        __builtin_amdgcn_sched_barrier(0);

        // ---- issue patch(sl+2) into the buffer just consumed ----
        if (sl + 2 < SN) {
            const unsigned short* base =
                fpad + (size_t)(sl + 2) * plane
                + ((fya[sl + 2] + 1) * Wp + (ea[sl + 2] + 4)) * CC;
            #pragma unroll
            for (int i = 0; i < 5; ++i) gll16(base + poff[i], &pbuf[ldso[i]]);
        }
        __builtin_amdgcn_sched_barrier(0);

        // ---- bilinear: per task 4 tap rows x 2 b64 reads -> 8 outputs ----
        {
            unsigned short* vrow = vol + ((size_t)(g * SN + sl) * NN + n) * K1P2;
            #pragma unroll
            for (int rep = 0; rep < 2; ++rep) {
                if (vld[rep]) {
                    int base = (p0b[rep] + off) * 68 + ij0a[rep];
                    s16x4 a0 = *(const s16x4*)&pcL[base],       a1 = *(const s16x4*)&pcL[base + 4];
                    s16x4 b0 = *(const s16x4*)&pcL[base + 68],  b1 = *(const s16x4*)&pcL[base + 72];
                    s16x4 c0 = *(const s16x4*)&pcL[base + 680], c1 = *(const s16x4*)&pcL[base + 684];
                    s16x4 d0 = *(const s16x4*)&pcL[base + 748], d1 = *(const s16x4*)&pcL[base + 752];
                    unsigned w[4];
                    #pragma unroll
                    for (int j = 0; j < 4; ++j) {
                        const int e0 = 2 * j, e1 = 2 * j + 1;
                        float v0 = w00 * b2f((unsigned short)(e0 < 4 ? a0[e0 & 3] : a1[e0 & 3]))
                                 + w10 * b2f((unsigned short)(e0 < 4 ? b0[e0 & 3] : b1[e0 & 3]))
                                 + w01 * b2f((unsigned short)(e0 < 4 ? c0[e0 & 3] : c1[e0 & 3]))
                                 + w11 * b2f((unsigned short)(e0 < 4 ? d0[e0 & 3] : d1[e0 & 3]));
                        float v1 = w00 * b2f((unsigned short)(e1 < 4 ? a0[e1 & 3] : a1[e1 & 3]))
                                 + w10 * b2f((unsigned short)(e1 < 4 ? b0[e1 & 3] : b1[e1 & 3]))
                                 + w01 * b2f((unsigned short)(e1 < 4 ? c0[e1 & 3] : c1[e1 & 3]))
                                 + w11 * b2f((unsigned short)(e1 < 4 ? d0[e1 & 3] : d1[e1 & 3]));
                        w[j] = (unsigned)f2b(v0) | ((unsigned)f2b(v1) << 16);
                    }
                    uint4 st; st.x = w[0]; st.y = w[1]; st.z = w[2]; st.w = w[3];
                    *(uint4*)(vrow + tau8[rep]) = st;
                }
            }
        }
    }
}

// ---------------------------------------------------------------------------
// Zero vol pad columns 2744..2751 (NaN shield for gemm1's K padding).
// ---------------------------------------------------------------------------
__global__ __launch_bounds__(256) void zpad_kernel(
    unsigned short* __restrict__ vol, int rows)
{
    int r = blockIdx.x * 256 + threadIdx.x;
    if (r < rows) {
        uint4 z; z.x = 0; z.y = 0; z.z = 0; z.w = 0;
        *(uint4*)(vol + (size_t)r * K1P2 + 2744) = z;
    }
}

// ---------------------------------------------------------------------------
// w1 (2401x384 f32) -> w1t (384x2752 bf16) with the bilinear K-permutation.
// ---------------------------------------------------------------------------
__global__ __launch_bounds__(256) void conv_w1_kernel(
    const float* __restrict__ w1, unsigned short* __restrict__ w1t)
{
    __shared__ float tile[32][33];
    const int kb = blockIdx.x * 32, nb = blockIdx.y * 32;
    const int tx = threadIdx.x & 31, ty = threadIdx.x >> 5;
    #pragma unroll
    for (int i = 0; i < 32; i += 8) {
        int kp = kb + ty + i;
        int k = -1;
        if (kp < 2744) {
            int tau = kp >> 3, r = kp & 7;
            int ab = tau / 7, blk = tau - 7 * ab;
            int ij = blk * 8 + r;
            if (ij < 49) k = ab * 49 + ij;
        }
        tile[ty + i][tx] = (k >= 0) ? w1[(size_t)k * H1 + nb + tx] : 0.f;
    }
    __syncthreads();
    #pragma unroll
    for (int i = 0; i < 32; i += 8)
        w1t[(size_t)(nb + ty + i) * K1P2 + kb + tx] = f2b(tile[tx][ty + i]);
}

// ---------------------------------------------------------------------------
// GEMM1: H = gelu(vol @ w1 + b1).  (rows x 2752) @ (2752 x 384) bf16.
// 512 threads, tile 128x384 (full N), 8 waves (2x4), wave tile 64x96.
// 3-buffer counted-vmcnt pipeline; 1 block/CU (LDS 96KB).
// ---------------------------------------------------------------------------
__global__ __launch_bounds__(512, 2) void gemm1_kernel(
    const unsigned short* __restrict__ A,   // rows x 2752
    const unsigned short* __restrict__ Bt,  // 384 x 2752 (= w1^T permuted)
    const float* __restrict__ bias,
    unsigned short* __restrict__ Hout)      // rows x 384
{
    __shared__ __align__(16) unsigned short As[3 * 128 * 32];  // 8KB/buf
    __shared__ __align__(16) unsigned short Bs[3 * 384 * 32];  // 24KB/buf
    const int h = blockIdx.x, q = gridDim.x >> 3;
    const int l = (h & 7) * q + (h >> 3);
    const int m0 = l * 128;
    const int t = threadIdx.x, lane = t & 63, wv = t >> 6;
    const int wm = wv >> 2, wn = wv & 3;           // 2 x 4 wave grid
    const int rsub = lane & 15, kq = lane >> 4;

    // A staging: granule g = t (512): row rA = g>>2, seg sA = (g&3)^((rA>>1)&3)
    const int rA = t >> 2, sA = (t & 3) ^ ((rA >> 1) & 3);
    const unsigned short* gA = A + (size_t)(m0 + rA) * K1P2 + sA * 8;
    const int chA = (t & ~63) * 8;                 // linear LDS dest (shorts)
    // B staging: granules g = t + 512*j, j=0..2: row rB = g>>2 (0..383)
    const unsigned short* gB[3];
    int chB[3];
    #pragma unroll
    for (int j = 0; j < 3; ++j) {
        int gg = t + 512 * j;
        int rB = gg >> 2, sB = (gg & 3) ^ ((rB >> 1) & 3);
        gB[j] = Bt + (size_t)rB * K1P2 + sB * 8;
        chB[j] = (t & ~63) * 8 + j * 4096;
    }

    f32x4 acc[4][6] = {};

    const int NSTEP = K1P2 / 32;  // 86
    #pragma unroll
    for (int p = 0; p < 3; ++p) {
        size_t ko = (size_t)p * 32;
        gll16(gA + ko, &As[p * 4096 + chA]);
        #pragma unroll
        for (int j = 0; j < 3; ++j)
            gll16(gB[j] + ko, &Bs[p * 12288 + chB[j]]);
    }
    int cur = 0;
    for (int st = 0; st < NSTEP; ++st) {
        const int rem = NSTEP - 1 - st;
        if (rem >= 2)      asm volatile("s_waitcnt vmcnt(8)" ::: "memory");
        else if (rem == 1) asm volatile("s_waitcnt vmcnt(4)" ::: "memory");
        else               asm volatile("s_waitcnt vmcnt(0)" ::: "memory");
        __builtin_amdgcn_s_barrier();
        __builtin_amdgcn_sched_barrier(0);
        const int lbA = cur * 4096, lbB = cur * 12288;
        bf16x8 af[4], bfr[6];
        #pragma unroll
        for (int mi = 0; mi < 4; ++mi) {
            int r = wm * 64 + mi * 16 + rsub;
            int phys = r * 4 + (kq ^ ((r >> 1) & 3));
            af[mi] = *(const bf16x8*)&As[lbA + phys * 8];
        }
        #pragma unroll
        for (int ni = 0; ni < 6; ++ni) {
            int r = wn * 96 + ni * 16 + rsub;
            int phys = r * 4 + (kq ^ ((r >> 1) & 3));
            bfr[ni] = *(const bf16x8*)&Bs[lbB + phys * 8];
        }
        __builtin_amdgcn_s_setprio(1);
        #pragma unroll
        for (int mi = 0; mi < 4; ++mi)
            #pragma unroll
            for (int ni = 0; ni < 6; ++ni)
                acc[mi][ni] = __builtin_amdgcn_mfma_f32_16x16x32_bf16(
                    af[mi], bfr[ni], acc[mi][ni], 0, 0, 0);
        __builtin_amdgcn_s_setprio(0);
        __builtin_amdgcn_sched_barrier(0);
        __builtin_amdgcn_s_barrier();
        __builtin_amdgcn_sched_barrier(0);
        if (st + 3 < NSTEP) {
            size_t ko = (size_t)(st + 3) * 32;
            gll16(gA + ko, &As[lbA + chA]);
            #pragma unroll
            for (int j = 0; j < 3; ++j)
                gll16(gB[j] + ko, &Bs[lbB + chB[j]]);
        }
        cur = (cur == 2) ? 0 : cur + 1;
    }
    #pragma unroll
    for (int mi = 0; mi < 4; ++mi) {
        int row = m0 + wm * 64 + mi * 16 + kq * 4;
        #pragma unroll
        for (int ni = 0; ni < 6; ++ni) {
            int col = wn * 96 + ni * 16 + rsub;
            float bcol = bias[col];
            #pragma unroll
            for (int r = 0; r < 4; ++r) {
                float x = acc[mi][ni][r] + bcol;
                float gg = 0.5f * x * (1.f + erff(x * 0.70710678118654752f));
                Hout[(size_t)(row + r) * H1 + col] = f2b(gg);
            }
        }
    }
}

// ---------------------------------------------------------------------------
// GEMM2: out slice = H @ w2 + b2 + time_emb.  (rows x 384) @ (384 x 256).
// ---------------------------------------------------------------------------
__global__ __launch_bounds__(256, 3) void gemm2_kernel(
    const unsigned short* __restrict__ A,   // rows x 384
    const unsigned short* __restrict__ Bt,  // 256 x 384 (= w2^T)
    const float* __restrict__ bias,
    const float* __restrict__ te,           // (8, 1110)
    float* __restrict__ out,                // (N, 8, 1110)
    int lv0)
{
    __shared__ __align__(16) unsigned short As[3 * 128 * 32];
    __shared__ __align__(16) unsigned short Bs[3 * 128 * 32];
    const int h = blockIdx.x, q = gridDim.x >> 3;
    const int l = (h & 7) * q + (h >> 3);
    const int m0 = (l >> 1) * 128, n0 = (l & 1) * 128;
    const int t = threadIdx.x, lane = t & 63, wv = t >> 6;
    const int wm = wv >> 1, wn = wv & 1;
    const int rsub = lane & 15, kq = lane >> 4;

    const int rA0 = t >> 2, sA0 = (t & 3) ^ ((rA0 >> 1) & 3);
    const int rA1 = (t + 256) >> 2, sA1 = ((t + 256) & 3) ^ ((rA1 >> 1) & 3);
    const unsigned short* gA0 = A  + (size_t)(m0 + rA0) * H1 + sA0 * 8;
    const unsigned short* gA1 = A  + (size_t)(m0 + rA1) * H1 + sA1 * 8;
    const unsigned short* gB0 = Bt + (size_t)(n0 + rA0) * H1 + sA0 * 8;
    const unsigned short* gB1 = Bt + (size_t)(n0 + rA1) * H1 + sA1 * 8;
    const int chunk0 = (t & ~63) * 8, chunk1 = (256 + (t & ~63)) * 8;

    f32x4 acc[4][4] = {};

    const int NSTEP = H1 / 32;  // 12
    #pragma unroll
    for (int p = 0; p < 3; ++p) {
        size_t ko = (size_t)p * 32;
        int lb = p * 4096;
        gll16(gA0 + ko, &As[lb + chunk0]); gll16(gA1 + ko, &As[lb + chunk1]);
        gll16(gB0 + ko, &Bs[lb + chunk0]); gll16(gB1 + ko, &Bs[lb + chunk1]);
    }
    int cur = 0;
    for (int st = 0; st < NSTEP; ++st) {
        const int rem = NSTEP - 1 - st;
        if (rem >= 2)      asm volatile("s_waitcnt vmcnt(8)" ::: "memory");
        else if (rem == 1) asm volatile("s_waitcnt vmcnt(4)" ::: "memory");
        else               asm volatile("s_waitcnt vmcnt(0)" ::: "memory");
        __builtin_amdgcn_s_barrier();
        __builtin_amdgcn_sched_barrier(0);
        const int lb = cur * 4096;
        bf16x8 af[4], bfr[4];
        #pragma unroll
        for (int mi = 0; mi < 4; ++mi) {
            int r = wm * 64 + mi * 16 + rsub;
            int phys = r * 4 + (kq ^ ((r >> 1) & 3));
            af[mi] = *(const bf16x8*)&As[lb + phys * 8];
        }
        #pragma unroll
        for (int ni = 0; ni < 4; ++ni) {
            int r = wn * 64 + ni * 16 + rsub;
            int phys = r * 4 + (kq ^ ((r >> 1) & 3));
            bfr[ni] = *(const bf16x8*)&Bs[lb + phys * 8];
        }
        __builtin_amdgcn_s_setprio(1);
        #pragma unroll
        for (int mi = 0; mi < 4; ++mi)
            #pragma unroll
            for (int ni = 0; ni < 4; ++ni)
                acc[mi][ni] = __builtin_amdgcn_mfma_f32_16x16x32_bf16(
                    af[mi], bfr[ni], acc[mi][ni], 0, 0, 0);
        __builtin_amdgcn_s_setprio(0);
        __builtin_amdgcn_sched_barrier(0);
        __builtin_amdgcn_s_barrier();
        __builtin_amdgcn_sched_barrier(0);
        if (st + 3 < NSTEP) {
            size_t ko = (size_t)(st + 3) * 32;
            gll16(gA0 + ko, &As[lb + chunk0]);
            gll16(gA1 + ko, &As[lb + chunk1]);
            gll16(gB0 + ko, &Bs[lb + chunk0]);
            gll16(gB1 + ko, &Bs[lb + chunk1]);
        }
        cur = (cur == 2) ? 0 : cur + 1;
    }
    #pragma unroll
    for (int mi = 0; mi < 4; ++mi) {
        int rowb = m0 + wm * 64 + mi * 16 + kq * 4;
        #pragma unroll
        for (int ni = 0; ni < 4; ++ni) {
            int col = n0 + wn * 64 + ni * 16 + rsub;
            float bcol = bias[col];
            #pragma unroll
            for (int r = 0; r < 4; ++r) {
                int row = rowb + r;
                int g = row >> 13, s = (row >> 10) & 7, n = row & 1023;
                int dcol = 2 + (lv0 + g) * H2 + col;
                out[((size_t)n * SN + s) * DOUT + dcol] =
                    acc[mi][ni][r] + bcol + te[s * DOUT + dcol];
            }
        }
    }
}

// ---------------------------------------------------------------------------
// Transpose + bf16-convert: in (K x Nw f32) -> out (Nw x Kp bf16), zero-pad.
// ---------------------------------------------------------------------------
__global__ __launch_bounds__(256) void conv_t_kernel(
    const float* __restrict__ in, unsigned short* __restrict__ outp,
    int K, int Nw, int Kp)
{
    __shared__ float tile[32][33];
    const int kb = blockIdx.x * 32, nb = blockIdx.y * 32;
    const int tx = threadIdx.x & 31, ty = threadIdx.x >> 5;
    #pragma unroll
    for (int i = 0; i < 32; i += 8) {
        int k = kb + ty + i, nn = nb + tx;
        tile[ty + i][tx] = (k < K && nn < Nw) ? in[(size_t)k * Nw + nn] : 0.f;
    }
    __syncthreads();
    #pragma unroll
    for (int i = 0; i < 32; i += 8) {
        int nn = nb + ty + i, k = kb + tx;
        if (nn < Nw) outp[(size_t)nn * Kp + k] = f2b(tile[tx][ty + i]);
    }
}

// Kernel D: vis, conf, rel_emb(84) + time_emb.
__global__ __launch_bounds__(128) void tail_kernel(
    const float* __restrict__ coords, const float* __restrict__ vis,
    const float* __restrict__ conf, const float* __restrict__ te,
    float* __restrict__ out)
{
    const int b = blockIdx.x;
    const int n = b >> 3, s = b & 7;
    const int d = threadIdx.x;
    if (d >= 86) return;
    const size_t ob = (size_t)b * DOUT;
    if (d == 0) {
        out[ob + 0] = vis[(size_t)s * NN + n] + te[s * DOUT + 0];
    } else if (d == 1) {
        out[ob + 1] = conf[(size_t)s * NN + n] + te[s * DOUT + 1];
    } else {
        int rd = d - 2;
        float cx = coords[((size_t)s * NN + n) * 2 + 0];
        float cy = coords[((size_t)s * NN + n) * 2 + 1];
        float rfx = 0.f, rfy = 0.f, rbx = 0.f, rby = 0.f;
        if (s < SN - 1) {
            rfx = cx - coords[((size_t)(s + 1) * NN + n) * 2 + 0];
            rfy = cy - coords[((size_t)(s + 1) * NN + n) * 2 + 1];
        }
        if (s > 0) {
            rbx = cx - coords[((size_t)(s - 1) * NN + n) * 2 + 0];
            rby = cy - coords[((size_t)(s - 1) * NN + n) * 2 + 1];
        }
        float r4[4] = {rfx / 128.f, rfy / 96.f, rbx / 128.f, rby / 96.f};
        float val;
        if (rd < 4) {
            val = r4[rd];
        } else if (rd < 44) {
            int q = rd - 4; int deg = q >> 2, comp = q & 3;
            val = sinf(r4[comp] * (float)(1 << deg));
        } else {
            int q = rd - 44; int deg = q >> 2, comp = q & 3;
            val = sinf(r4[comp] * (float)(1 << deg) + 1.57079632679489662f);
        }
        int od = 1026 + rd;
        out[ob + od] = val + te[s * DOUT + od];
    }
}

extern "C" void kernel_launch(void* const* d_in, const int* in_sizes, int n_in,
                              void* d_out, int out_size, void* d_ws, size_t ws_size,
                              hipStream_t stream) {
    const float* fmaps[4] = {(const float*)d_in[0], (const float*)d_in[2],
                             (const float*)d_in[4], (const float*)d_in[6]};
    const float* track[4] = {(const float*)d_in[1], (const float*)d_in[3],
                             (const float*)d_in[5], (const float*)d_in[7]};
    const float* coords = (const float*)d_in[8];
    const float* vis    = (const float*)d_in[9];
    const float* conf   = (const float*)d_in[10];
    const float* w1     = (const float*)d_in[11];
    const float* b1     = (const float*)d_in[12];
    const float* w2     = (const float*)d_in[13];
    const float* b2     = (const float*)d_in[14];
    const float* te     = (const float*)d_in[15];
    float* out = (float*)d_out;

    const int Hs[4] = {96, 48, 24, 12};
    const int Ws[4] = {128, 64, 32, 16};

    // ---- workspace layout ----
    char* wsb = (char*)d_ws;
    unsigned short* w1t = (unsigned short*)wsb;
    size_t off = (size_t)H1 * K1P2 * 2;
    unsigned short* w2t = (unsigned short*)(wsb + off);
    off += (size_t)H2 * H1 * 2;
    unsigned short* fpad[4];
    for (int l = 0; l < 4; ++l) {
        fpad[l] = (unsigned short*)(wsb + off);
        off += (size_t)SN * (Hs[l] + 8) * (Ws[l] + 8) * CC * 2;
    }
    off += 512;  // slack
    const size_t fixed = off;
    int n_lv = 4;
    while (n_lv > 1 &&
           fixed + (size_t)n_lv * SN * NN * (K1P2 + H1) * 2 > ws_size)
        n_lv >>= 1;
    unsigned short* volb = (unsigned short*)(wsb + fixed);
    unsigned short* hb   = volb + (size_t)n_lv * SN * NN * K1P2;

    // ---- weight prep + fmap conversion + vol K-pad zero ----
    conv_w1_kernel<<<dim3(K1P2 / 32, H1 / 32), 256, 0, stream>>>(w1, w1t);
    conv_t_kernel<<<dim3(H1 / 32, H2 / 32), 256, 0, stream>>>(w2, w2t, H1, H2, H1);
    for (int l = 0; l < 4; ++l)
        conv_fmap_kernel<<<SN * (Hs[l] + 8), 256, 0, stream>>>(
            fmaps[l], fpad[l], Hs[l], Ws[l]);
    zpad_kernel<<<(n_lv * SN * NN + 255) / 256, 256, 0, stream>>>(
        volb, n_lv * SN * NN);

    for (int lv0 = 0; lv0 < 4; lv0 += n_lv) {
        sample_vol_kernel<<<n_lv * NN, 256, 0, stream>>>(
            fpad[0], fpad[1], fpad[2], fpad[3],
            track[0], track[1], track[2], track[3],
            coords, volb, lv0);
        const int rows = n_lv * SN * NN;
        gemm1_kernel<<<rows / 128, 512, 0, stream>>>(volb, w1t, b1, hb);
        gemm2_kernel<<<(rows / 128) * 2, 256, 0, stream>>>(hb, w2t, b2, te, out, lv0);
    }
    tail_kernel<<<SN * NN, 128, 0, stream>>>(coords, vis, conf, te, out);
}

// Round 15
// 343.385 us; speedup vs baseline: 1.0911x; 1.0911x over previous
//
#include <hip/hip_runtime.h>
#include <math.h>

// ---------------------------------------------------------------------------
// CoTracker correlation-embedding pipeline, bf16 MFMA, HWC-padded fmaps.
// Round 14: gemm1 reverted to 128x128/3-block config; gemm1+gemm2 switched
// to distance-2 prefetch on 3 buffers => ONE barrier per K-step (vmcnt(4)).
// sample_vol = R12 (2-deep patch pipeline, permuted-K vol, b64 taps).
// Inputs: 0:fmaps0 1:track0 2:fmaps1 3:track1 4:fmaps2 5:track2 6:fmaps3
//         7:track3 8:coords 9:vis 10:conf 11:w1 12:b1 13:w2 14:b2 15:time_emb
// Output: (1,N,8,1110) f32.
// ---------------------------------------------------------------------------

#define SN 8
#define NN 1024
#define CC 128
#define K1P2 2752   // 343*8 = 2744 data + 8 pad (86 K-steps of 32)
#define H1 384
#define H2 256
#define DOUT 1110

typedef short bf16x8 __attribute__((ext_vector_type(8)));
typedef short s16x4 __attribute__((ext_vector_type(4)));
typedef float f32x4 __attribute__((ext_vector_type(4)));

__device__ inline unsigned short f2b(float x) {  // RTNE f32 -> bf16
    union { float f; unsigned u; } v; v.f = x;
    unsigned r = v.u + 0x7FFFu + ((v.u >> 16) & 1u);
    return (unsigned short)(r >> 16);
}
__device__ inline float b2f(unsigned short u) {
    union { unsigned u; float f; } v; v.u = (unsigned)u << 16; return v.f;
}
__device__ inline void gll16(const void* g, void* l) {
    __builtin_amdgcn_global_load_lds(
        (const __attribute__((address_space(1))) void*)g,
        (__attribute__((address_space(3))) void*)l, 16, 0, 0);
}
// XOR-swizzled LDS index (shorts) for [rows][128] bf16 MFMA operand tiles.
__device__ inline int swz(int row, int g) {
    return row * 128 + ((g ^ (row & 7)) << 3);
}

// ---------------------------------------------------------------------------
// fmap fp32 (S,C,H,W) -> bf16 HWC padded (S, H+8, W+8, C), border replicate.
// ---------------------------------------------------------------------------
__global__ __launch_bounds__(256) void conv_fmap_kernel(
    const float* __restrict__ in, unsigned short* __restrict__ outp,
    int H, int W)
{
    const int Hp = H + 8, Wp = W + 8;
    const int s = blockIdx.x / Hp, yp = blockIdx.x % Hp;
    const int y = min(max(yp - 4, 0), H - 1);
    const float* src = in + (size_t)s * CC * H * W + (size_t)y * W;
    unsigned short* dst = outp + ((size_t)s * Hp + yp) * Wp * CC;
    for (int idx = threadIdx.x; idx < Wp * CC; idx += 256) {
        int xp = idx >> 7, c = idx & 127;
        int x = min(max(xp - 4, 0), W - 1);
        dst[idx] = f2b(src[(size_t)c * H * W + x]);
    }
}

// ---------------------------------------------------------------------------
// Kernel A (fused over levels): block -> (g = blk>>10, n = blk&1023).
// 2-deep patch pipeline (bufB aliases trk after register-hoist). Per s:
// [counted vmcnt + bar] MFMA pc -> pcL bf16 [lgkm bar] issue patch(sl+2)
// -> bilinear (b64 taps) -> permuted-K vol (dwordx4 stores).
// LDS 50.6KB -> 3 blocks/CU.
// ---------------------------------------------------------------------------
__global__ __launch_bounds__(256, 3) void sample_vol_kernel(
    const unsigned short* __restrict__ fq0, const unsigned short* __restrict__ fq1,
    const unsigned short* __restrict__ fq2, const unsigned short* __restrict__ fq3,
    const float* __restrict__ tk0, const float* __restrict__ tk1,
    const float* __restrict__ tk2, const float* __restrict__ tk3,
    const float* __restrict__ coords,        // (8, N, 2) f32
    unsigned short* __restrict__ vol,        // (n_lv*8*N, 2752) bf16 permuted-K
    int lv0)
{
    __shared__ __align__(16) unsigned short bufA[80 * 128]; // 20 KB
    __shared__ __align__(16) unsigned short bufB[80 * 128]; // 20 KB (trk alias)
    __shared__ __align__(16) unsigned short pcL[80 * 68];   // 10.6 KB
    const int n = blockIdx.x & 1023, g = blockIdx.x >> 10;
    const int lvl = lv0 + g;
    const unsigned short* fpad = (lvl == 0) ? fq0 : (lvl == 1) ? fq1
                               : (lvl == 2) ? fq2 : fq3;
    const float* track = (lvl == 0) ? tk0 : (lvl == 1) ? tk1
                       : (lvl == 2) ? tk2 : tk3;
    const int Wp = (128 >> lvl) + 8;
    const int t = threadIdx.x;
    const int lane = t & 63, wv = t >> 6;
    const int rsub = lane & 15, kq = lane >> 4;
    const float inv = 1.0f / (float)(1 << lvl);
    const size_t plane = (size_t)((96 >> lvl) + 8) * Wp * CC;

    int poff[5], ldso[5];
    #pragma unroll
    for (int i = 0; i < 5; ++i) {
        int task64 = wv * 5 + i;
        int point = task64 * 4 + (lane >> 4);  // patch row 0..79
        int v = point / 10, xs = point - v * 10;
        int j = (lane & 15) ^ (point & 7);
        poff[i] = (v * Wp + xs) * CC + j * 8;
        ldso[i] = task64 * 512;
    }

    float cxa[SN], cya[SN];
    int fxa[SN], fya[SN], ea[SN];
    #pragma unroll
    for (int s = 0; s < SN; ++s) {
        float2 c2 = *(const float2*)&coords[((size_t)s * NN + n) * 2];
        cxa[s] = c2.x * inv; cya[s] = c2.y * inv;
        fxa[s] = (int)floorf(cxa[s]);
        fya[s] = (int)floorf(cya[s]);
        ea[s] = (fxa[s] - 3) & ~1;
    }

    int p0b[2], ij0a[2], tau8[2]; bool vld[2];
    #pragma unroll
    for (int rep = 0; rep < 2; ++rep) {
        int tau = t + rep * 256;
        vld[rep] = (tau < 343);
        int tt = vld[rep] ? tau : 0;
        int ab = tt / 7, blk = tt - 7 * ab;
        int a = ab / 7, b = ab - 7 * a;
        p0b[rep] = b * 10 + a;
        ij0a[rep] = blk * 8;
        tau8[rep] = tt * 8;
    }

    // patch s=0 -> bufA
    {
        const unsigned short* base =
            fpad + ((fya[0] + 1) * Wp + (ea[0] + 4)) * CC;
        #pragma unroll
        for (int i = 0; i < 5; ++i) gll16(base + poff[i], &bufA[ldso[i]]);
    }
    // track[n] -> bufB (trk layout, swizzled), once
    for (int task = t; task < 49 * 16; task += 256) {
        int row = task >> 4, gg = task & 15;
        const float* srcp = &track[((size_t)row * NN + n) * CC + gg * 8];
        float4 f0 = *(const float4*)srcp;
        float4 f1 = *(const float4*)(srcp + 4);
        bf16x8 v8;
        v8[0] = f2b(f0.x); v8[1] = f2b(f0.y); v8[2] = f2b(f0.z); v8[3] = f2b(f0.w);
        v8[4] = f2b(f1.x); v8[5] = f2b(f1.y); v8[6] = f2b(f1.z); v8[7] = f2b(f1.w);
        *(bf16x8*)&bufB[swz(row, gg)] = v8;
    }
    {
        unsigned* T32 = (unsigned*)bufB;
        for (int i = t; i < 15 * 64; i += 256) T32[49 * 64 + i] = 0;
    }
    asm volatile("s_waitcnt lgkmcnt(0)" ::: "memory");
    __builtin_amdgcn_sched_barrier(0);
    __builtin_amdgcn_s_barrier();
    bf16x8 tf[4];
    #pragma unroll
    for (int kk = 0; kk < 4; ++kk)
        tf[kk] = *(const bf16x8*)&bufB[swz(wv * 16 + rsub, kk * 4 + kq)];
    asm volatile("s_waitcnt lgkmcnt(0)" ::: "memory");
    __builtin_amdgcn_sched_barrier(0);
    __builtin_amdgcn_s_barrier();
    __builtin_amdgcn_sched_barrier(0);
    // patch s=1 -> bufB (now free)
    {
        const unsigned short* base =
            fpad + plane + ((fya[1] + 1) * Wp + (ea[1] + 4)) * CC;
        #pragma unroll
        for (int i = 0; i < 5; ++i) gll16(base + poff[i], &bufB[ldso[i]]);
    }

    #pragma unroll
    for (int sl = 0; sl < SN; ++sl) {
        unsigned short* pbuf = (sl & 1) ? bufB : bufA;
        const float wx = cxa[sl] - (float)fxa[sl], wy = cya[sl] - (float)fya[sl];
        const float w00 = (1.f - wx) * (1.f - wy), w10 = wx * (1.f - wy);
        const float w01 = (1.f - wx) * wy,         w11 = wx * wy;
        const int off = fxa[sl] - 3 - ea[sl];

        if (sl == 0) {
            asm volatile("s_waitcnt vmcnt(5) lgkmcnt(0)" ::: "memory");
        } else if (sl == 1) {
            if (wv < 2) asm volatile("s_waitcnt vmcnt(7) lgkmcnt(0)" ::: "memory");
            else        asm volatile("s_waitcnt vmcnt(6) lgkmcnt(0)" ::: "memory");
        } else if (sl == SN - 1) {
            if (wv < 2) asm volatile("s_waitcnt vmcnt(4) lgkmcnt(0)" ::: "memory");
            else        asm volatile("s_waitcnt vmcnt(2) lgkmcnt(0)" ::: "memory");
        } else {
            if (wv < 2) asm volatile("s_waitcnt vmcnt(9) lgkmcnt(0)" ::: "memory");
            else        asm volatile("s_waitcnt vmcnt(7) lgkmcnt(0)" ::: "memory");
        }
        __builtin_amdgcn_sched_barrier(0);
        __builtin_amdgcn_s_barrier();
        __builtin_amdgcn_sched_barrier(0);

        // ---- MFMA: pc[80][64] = patch(80x128) . trk(64x128)^T -> pcL bf16 --
        {
            f32x4 acc[5] = {};
            __builtin_amdgcn_s_setprio(1);
            #pragma unroll
            for (int kk = 0; kk < 4; ++kk) {
                int gg = kk * 4 + kq;
                #pragma unroll
                for (int ti = 0; ti < 5; ++ti) {
                    bf16x8 a = *(const bf16x8*)&pbuf[swz(ti * 16 + rsub, gg)];
                    acc[ti] = __builtin_amdgcn_mfma_f32_16x16x32_bf16(a, tf[kk], acc[ti], 0, 0, 0);
                }
            }
            __builtin_amdgcn_s_setprio(0);
            const int col = wv * 16 + rsub;
            #pragma unroll
            for (int ti = 0; ti < 5; ++ti)
                #pragma unroll
                for (int r = 0; r < 4; ++r)
                    pcL[(ti * 16 + kq * 4 + r) * 68 + col] = f2b(acc[ti][r]);
        }
        asm volatile("s_waitcnt lgkmcnt(0)" ::: "memory");
        __builtin_amdgcn_s_barrier();
        __builtin_amdgcn_sched_barrier(0);

        // ---- issue patch(sl+2) into the buffer just consumed ----
        if (sl + 2 < SN) {
            const unsigned short* base =
                fpad + (size_t)(sl + 2) * plane
                + ((fya[sl + 2] + 1) * Wp + (ea[sl + 2] + 4)) * CC;
            #pragma unroll
            for (int i = 0; i < 5; ++i) gll16(base + poff[i], &pbuf[ldso[i]]);
        }
        __builtin_amdgcn_sched_barrier(0);

        // ---- bilinear: per task 4 tap rows x 2 b64 reads -> 8 outputs ----
        {
            unsigned short* vrow = vol + ((size_t)(g * SN + sl) * NN + n) * K1P2;
            #pragma unroll
            for (int rep = 0; rep < 2; ++rep) {
                if (vld[rep]) {
                    int base = (p0b[rep] + off) * 68 + ij0a[rep];
                    s16x4 a0 = *(const s16x4*)&pcL[base],       a1 = *(const s16x4*)&pcL[base + 4];
                    s16x4 b0 = *(const s16x4*)&pcL[base + 68],  b1 = *(const s16x4*)&pcL[base + 72];
                    s16x4 c0 = *(const s16x4*)&pcL[base + 680], c1 = *(const s16x4*)&pcL[base + 684];
                    s16x4 d0 = *(const s16x4*)&pcL[base + 748], d1 = *(const s16x4*)&pcL[base + 752];
                    unsigned w[4];
                    #pragma unroll
                    for (int j = 0; j < 4; ++j) {
                        const int e0 = 2 * j, e1 = 2 * j + 1;
                        float v0 = w00 * b2f((unsigned short)(e0 < 4 ? a0[e0 & 3] : a1[e0 & 3]))
                                 + w10 * b2f((unsigned short)(e0 < 4 ? b0[e0 & 3] : b1[e0 & 3]))
                                 + w01 * b2f((unsigned short)(e0 < 4 ? c0[e0 & 3] : c1[e0 & 3]))
                                 + w11 * b2f((unsigned short)(e0 < 4 ? d0[e0 & 3] : d1[e0 & 3]));
                        float v1 = w00 * b2f((unsigned short)(e1 < 4 ? a0[e1 & 3] : a1[e1 & 3]))
                                 + w10 * b2f((unsigned short)(e1 < 4 ? b0[e1 & 3] : b1[e1 & 3]))
                                 + w01 * b2f((unsigned short)(e1 < 4 ? c0[e1 & 3] : c1[e1 & 3]))
                                 + w11 * b2f((unsigned short)(e1 < 4 ? d0[e1 & 3] : d1[e1 & 3]));
                        w[j] = (unsigned)f2b(v0) | ((unsigned)f2b(v1) << 16);
                    }
                    uint4 st; st.x = w[0]; st.y = w[1]; st.z = w[2]; st.w = w[3];
                    *(uint4*)(vrow + tau8[rep]) = st;
                }
            }
        }
    }
}

// ---------------------------------------------------------------------------
// Zero vol pad columns 2744..2751 (NaN shield for gemm1's K padding).
// ---------------------------------------------------------------------------
__global__ __launch_bounds__(256) void zpad_kernel(
    unsigned short* __restrict__ vol, int rows)
{
    int r = blockIdx.x * 256 + threadIdx.x;
    if (r < rows) {
        uint4 z; z.x = 0; z.y = 0; z.z = 0; z.w = 0;
        *(uint4*)(vol + (size_t)r * K1P2 + 2744) = z;
    }
}

// ---------------------------------------------------------------------------
// w1 (2401x384 f32) -> w1t (384x2752 bf16) with the bilinear K-permutation.
// ---------------------------------------------------------------------------
__global__ __launch_bounds__(256) void conv_w1_kernel(
    const float* __restrict__ w1, unsigned short* __restrict__ w1t)
{
    __shared__ float tile[32][33];
    const int kb = blockIdx.x * 32, nb = blockIdx.y * 32;
    const int tx = threadIdx.x & 31, ty = threadIdx.x >> 5;
    #pragma unroll
    for (int i = 0; i < 32; i += 8) {
        int kp = kb + ty + i;
        int k = -1;
        if (kp < 2744) {
            int tau = kp >> 3, r = kp & 7;
            int ab = tau / 7, blk = tau - 7 * ab;
            int ij = blk * 8 + r;
            if (ij < 49) k = ab * 49 + ij;
        }
        tile[ty + i][tx] = (k >= 0) ? w1[(size_t)k * H1 + nb + tx] : 0.f;
    }
    __syncthreads();
    #pragma unroll
    for (int i = 0; i < 32; i += 8)
        w1t[(size_t)(nb + ty + i) * K1P2 + kb + tx] = f2b(tile[tx][ty + i]);
}

// ---------------------------------------------------------------------------
// GEMM1: H = gelu(vol @ w1 + b1).  (rows x 2752) @ (2752 x 384) bf16.
// 3-buffer, prefetch distance 2 => ONE barrier per K-step, vmcnt(4) steady.
// Restage target (st+2)%3 == (st-1)%3: consumed last iter, reads retired
// before any wave passed this iter's barrier (MFMA lgkm-drained them).
// ---------------------------------------------------------------------------
__global__ __launch_bounds__(256, 3) void gemm1_kernel(
    const unsigned short* __restrict__ A,   // rows x 2752
    const unsigned short* __restrict__ Bt,  // 384 x 2752 (= w1^T permuted)
    const float* __restrict__ bias,
    unsigned short* __restrict__ Hout)      // rows x 384
{
    __shared__ __align__(16) unsigned short As[3 * 128 * 32];
    __shared__ __align__(16) unsigned short Bs[3 * 128 * 32];
    const int h = blockIdx.x, q = gridDim.x >> 3;
    const int l = (h & 7) * q + (h >> 3);
    const int m0 = (l / 3) * 128, n0 = (l % 3) * 128;
    const int t = threadIdx.x, lane = t & 63, wv = t >> 6;
    const int wm = wv >> 1, wn = wv & 1;
    const int rsub = lane & 15, kq = lane >> 4;

    const int rA0 = t >> 2, sA0 = (t & 3) ^ ((rA0 >> 1) & 3);
    const int rA1 = (t + 256) >> 2, sA1 = ((t + 256) & 3) ^ ((rA1 >> 1) & 3);
    const unsigned short* gA0 = A  + (size_t)(m0 + rA0) * K1P2 + sA0 * 8;
    const unsigned short* gA1 = A  + (size_t)(m0 + rA1) * K1P2 + sA1 * 8;
    const unsigned short* gB0 = Bt + (size_t)(n0 + rA0) * K1P2 + sA0 * 8;
    const unsigned short* gB1 = Bt + (size_t)(n0 + rA1) * K1P2 + sA1 * 8;
    const int chunk0 = (t & ~63) * 8, chunk1 = (256 + (t & ~63)) * 8;

    f32x4 acc[4][4] = {};

    const int NSTEP = K1P2 / 32;  // 86
    #pragma unroll
    for (int p = 0; p < 2; ++p) {  // prologue: tiles 0,1
        size_t ko = (size_t)p * 32;
        int lb = p * 4096;
        gll16(gA0 + ko, &As[lb + chunk0]); gll16(gA1 + ko, &As[lb + chunk1]);
        gll16(gB0 + ko, &Bs[lb + chunk0]); gll16(gB1 + ko, &Bs[lb + chunk1]);
    }
    int cur = 0, nxt = 2;
    for (int st = 0; st < NSTEP; ++st) {
        if (st + 1 < NSTEP) asm volatile("s_waitcnt vmcnt(4)" ::: "memory");
        else                asm volatile("s_waitcnt vmcnt(0)" ::: "memory");
        __builtin_amdgcn_s_barrier();
        __builtin_amdgcn_sched_barrier(0);
        // issue tile st+2 into buffer (st+2)%3 (= (st-1)%3, reads retired)
        if (st + 2 < NSTEP) {
            size_t ko = (size_t)(st + 2) * 32;
            int lb = nxt * 4096;
            gll16(gA0 + ko, &As[lb + chunk0]);
            gll16(gA1 + ko, &As[lb + chunk1]);
            gll16(gB0 + ko, &Bs[lb + chunk0]);
            gll16(gB1 + ko, &Bs[lb + chunk1]);
        }
        const int lb = cur * 4096;
        bf16x8 af[4], bfr[4];
        #pragma unroll
        for (int mi = 0; mi < 4; ++mi) {
            int r = wm * 64 + mi * 16 + rsub;
            int phys = r * 4 + (kq ^ ((r >> 1) & 3));
            af[mi] = *(const bf16x8*)&As[lb + phys * 8];
        }
        #pragma unroll
        for (int ni = 0; ni < 4; ++ni) {
            int r = wn * 64 + ni * 16 + rsub;
            int phys = r * 4 + (kq ^ ((r >> 1) & 3));
            bfr[ni] = *(const bf16x8*)&Bs[lb + phys * 8];
        }
        __builtin_amdgcn_s_setprio(1);
        #pragma unroll
        for (int mi = 0; mi < 4; ++mi)
            #pragma unroll
            for (int ni = 0; ni < 4; ++ni)
                acc[mi][ni] = __builtin_amdgcn_mfma_f32_16x16x32_bf16(
                    af[mi], bfr[ni], acc[mi][ni], 0, 0, 0);
        __builtin_amdgcn_s_setprio(0);
        cur = (cur == 2) ? 0 : cur + 1;
        nxt = (nxt == 2) ? 0 : nxt + 1;
    }
    #pragma unroll
    for (int mi = 0; mi < 4; ++mi) {
        int row = m0 + wm * 64 + mi * 16 + kq * 4;
        #pragma unroll
        for (int ni = 0; ni < 4; ++ni) {
            int col = n0 + wn * 64 + ni * 16 + rsub;
            float bcol = bias[col];
            #pragma unroll
            for (int r = 0; r < 4; ++r) {
                float x = acc[mi][ni][r] + bcol;
                float gg = 0.5f * x * (1.f + erff(x * 0.70710678118654752f));
                Hout[(size_t)(row + r) * H1 + col] = f2b(gg);
            }
        }
    }
}

// ---------------------------------------------------------------------------
// GEMM2: out slice = H @ w2 + b2 + time_emb.  (rows x 384) @ (384 x 256).
// Same distance-2 one-barrier scheme.
// ---------------------------------------------------------------------------
__global__ __launch_bounds__(256, 3) void gemm2_kernel(
    const unsigned short* __restrict__ A,   // rows x 384
    const unsigned short* __restrict__ Bt,  // 256 x 384 (= w2^T)
    const float* __restrict__ bias,
    const float* __restrict__ te,           // (8, 1110)
    float* __restrict__ out,                // (N, 8, 1110)
    int lv0)
{
    __shared__ __align__(16) unsigned short As[3 * 128 * 32];
    __shared__ __align__(16) unsigned short Bs[3 * 128 * 32];
    const int h = blockIdx.x, q = gridDim.x >> 3;
    const int l = (h & 7) * q + (h >> 3);
    const int m0 = (l >> 1) * 128, n0 = (l & 1) * 128;
    const int t = threadIdx.x, lane = t & 63, wv = t >> 6;
    const int wm = wv >> 1, wn = wv & 1;
    const int rsub = lane & 15, kq = lane >> 4;

    const int rA0 = t >> 2, sA0 = (t & 3) ^ ((rA0 >> 1) & 3);
    const int rA1 = (t + 256) >> 2, sA1 = ((t + 256) & 3) ^ ((rA1 >> 1) & 3);
    const unsigned short* gA0 = A  + (size_t)(m0 + rA0) * H1 + sA0 * 8;
    const unsigned short* gA1 = A  + (size_t)(m0 + rA1) * H1 + sA1 * 8;
    const unsigned short* gB0 = Bt + (size_t)(n0 + rA0) * H1 + sA0 * 8;
    const unsigned short* gB1 = Bt + (size_t)(n0 + rA1) * H1 + sA1 * 8;
    const int chunk0 = (t & ~63) * 8, chunk1 = (256 + (t & ~63)) * 8;

    f32x4 acc[4][4] = {};

    const int NSTEP = H1 / 32;  // 12
    #pragma unroll
    for (int p = 0; p < 2; ++p) {
        size_t ko = (size_t)p * 32;
        int lb = p * 4096;
        gll16(gA0 + ko, &As[lb + chunk0]); gll16(gA1 + ko, &As[lb + chunk1]);
        gll16(gB0 + ko, &Bs[lb + chunk0]); gll16(gB1 + ko, &Bs[lb + chunk1]);
    }
    int cur = 0, nxt = 2;
    for (int st = 0; st < NSTEP; ++st) {
        if (st + 1 < NSTEP) asm volatile("s_waitcnt vmcnt(4)" ::: "memory");
        else                asm volatile("s_waitcnt vmcnt(0)" ::: "memory");
        __builtin_amdgcn_s_barrier();
        __builtin_amdgcn_sched_barrier(0);
        if (st + 2 < NSTEP) {
            size_t ko = (size_t)(st + 2) * 32;
            int lb = nxt * 4096;
            gll16(gA0 + ko, &As[lb + chunk0]);
            gll16(gA1 + ko, &As[lb + chunk1]);
            gll16(gB0 + ko, &Bs[lb + chunk0]);
            gll16(gB1 + ko, &Bs[lb + chunk1]);
        }
        const int lb = cur * 4096;
        bf16x8 af[4], bfr[4];
        #pragma unroll
        for (int mi = 0; mi < 4; ++mi) {
            int r = wm * 64 + mi * 16 + rsub;
            int phys = r * 4 + (kq ^ ((r >> 1) & 3));
            af[mi] = *(const bf16x8*)&As[lb + phys * 8];
        }
        #pragma unroll
        for (int ni = 0; ni < 4; ++ni) {
            int r = wn * 64 + ni * 16 + rsub;
            int phys = r * 4 + (kq ^ ((r >> 1) & 3));
            bfr[ni] = *(const bf16x8*)&Bs[lb + phys * 8];
        }
        __builtin_amdgcn_s_setprio(1);
        #pragma unroll
        for (int mi = 0; mi < 4; ++mi)
            #pragma unroll
            for (int ni = 0; ni < 4; ++ni)
                acc[mi][ni] = __builtin_amdgcn_mfma_f32_16x16x32_bf16(
                    af[mi], bfr[ni], acc[mi][ni], 0, 0, 0);
        __builtin_amdgcn_s_setprio(0);
        cur = (cur == 2) ? 0 : cur + 1;
        nxt = (nxt == 2) ? 0 : nxt + 1;
    }
    #pragma unroll
    for (int mi = 0; mi < 4; ++mi) {
        int rowb = m0 + wm * 64 + mi * 16 + kq * 4;
        #pragma unroll
        for (int ni = 0; ni < 4; ++ni) {
            int col = n0 + wn * 64 + ni * 16 + rsub;
            float bcol = bias[col];
            #pragma unroll
            for (int r = 0; r < 4; ++r) {
                int row = rowb + r;
                int g = row >> 13, s = (row >> 10) & 7, n = row & 1023;
                int dcol = 2 + (lv0 + g) * H2 + col;
                out[((size_t)n * SN + s) * DOUT + dcol] =
                    acc[mi][ni][r] + bcol + te[s * DOUT + dcol];
            }
        }
    }
}

// ---------------------------------------------------------------------------
// Transpose + bf16-convert: in (K x Nw f32) -> out (Nw x Kp bf16), zero-pad.
// ---------------------------------------------------------------------------
__global__ __launch_bounds__(256) void conv_t_kernel(
    const float* __restrict__ in, unsigned short* __restrict__ outp,
    int K, int Nw, int Kp)
{
    __shared__ float tile[32][33];
    const int kb = blockIdx.x * 32, nb = blockIdx.y * 32;
    const int tx = threadIdx.x & 31, ty = threadIdx.x >> 5;
    #pragma unroll
    for (int i = 0; i < 32; i += 8) {
        int k = kb + ty + i, nn = nb + tx;
        tile[ty + i][tx] = (k < K && nn < Nw) ? in[(size_t)k * Nw + nn] : 0.f;
    }
    __syncthreads();
    #pragma unroll
    for (int i = 0; i < 32; i += 8) {
        int nn = nb + ty + i, k = kb + tx;
        if (nn < Nw) outp[(size_t)nn * Kp + k] = f2b(tile[tx][ty + i]);
    }
}

// Kernel D: vis, conf, rel_emb(84) + time_emb.
__global__ __launch_bounds__(128) void tail_kernel(
    const float* __restrict__ coords, const float* __restrict__ vis,
    const float* __restrict__ conf, const float* __restrict__ te,
    float* __restrict__ out)
{
    const int b = blockIdx.x;
    const int n = b >> 3, s = b & 7;
    const int d = threadIdx.x;
    if (d >= 86) return;
    const size_t ob = (size_t)b * DOUT;
    if (d == 0) {
        out[ob + 0] = vis[(size_t)s * NN + n] + te[s * DOUT + 0];
    } else if (d == 1) {
        out[ob + 1] = conf[(size_t)s * NN + n] + te[s * DOUT + 1];
    } else {
        int rd = d - 2;
        float cx = coords[((size_t)s * NN + n) * 2 + 0];
        float cy = coords[((size_t)s * NN + n) * 2 + 1];
        float rfx = 0.f, rfy = 0.f, rbx = 0.f, rby = 0.f;
        if (s < SN - 1) {
            rfx = cx - coords[((size_t)(s + 1) * NN + n) * 2 + 0];
            rfy = cy - coords[((size_t)(s + 1) * NN + n) * 2 + 1];
        }
        if (s > 0) {
            rbx = cx - coords[((size_t)(s - 1) * NN + n) * 2 + 0];
            rby = cy - coords[((size_t)(s - 1) * NN + n) * 2 + 1];
        }
        float r4[4] = {rfx / 128.f, rfy / 96.f, rbx / 128.f, rby / 96.f};
        float val;
        if (rd < 4) {
            val = r4[rd];
        } else if (rd < 44) {
            int q = rd - 4; int deg = q >> 2, comp = q & 3;
            val = sinf(r4[comp] * (float)(1 << deg));
        } else {
            int q = rd - 44; int deg = q >> 2, comp = q & 3;
            val = sinf(r4[comp] * (float)(1 << deg) + 1.57079632679489662f);
        }
        int od = 1026 + rd;
        out[ob + od] = val + te[s * DOUT + od];
    }
}

extern "C" void kernel_launch(void* const* d_in, const int* in_sizes, int n_in,
                              void* d_out, int out_size, void* d_ws, size_t ws_size,
                              hipStream_t stream) {
    const float* fmaps[4] = {(const float*)d_in[0], (const float*)d_in[2],
                             (const float*)d_in[4], (const float*)d_in[6]};
    const float* track[4] = {(const float*)d_in[1], (const float*)d_in[3],
                             (const float*)d_in[5], (const float*)d_in[7]};
    const float* coords = (const float*)d_in[8];
    const float* vis    = (const float*)d_in[9];
    const float* conf   = (const float*)d_in[10];
    const float* w1     = (const float*)d_in[11];
    const float* b1     = (const float*)d_in[12];
    const float* w2     = (const float*)d_in[13];
    const float* b2     = (const float*)d_in[14];
    const float* te     = (const float*)d_in[15];
    float* out = (float*)d_out;

    const int Hs[4] = {96, 48, 24, 12};
    const int Ws[4] = {128, 64, 32, 16};

    // ---- workspace layout ----
    char* wsb = (char*)d_ws;
    unsigned short* w1t = (unsigned short*)wsb;
    size_t off = (size_t)H1 * K1P2 * 2;
    unsigned short* w2t = (unsigned short*)(wsb + off);
    off += (size_t)H2 * H1 * 2;
    unsigned short* fpad[4];
    for (int l = 0; l < 4; ++l) {
        fpad[l] = (unsigned short*)(wsb + off);
        off += (size_t)SN * (Hs[l] + 8) * (Ws[l] + 8) * CC * 2;
    }
    off += 512;  // slack
    const size_t fixed = off;
    int n_lv = 4;
    while (n_lv > 1 &&
           fixed + (size_t)n_lv * SN * NN * (K1P2 + H1) * 2 > ws_size)
        n_lv >>= 1;
    unsigned short* volb = (unsigned short*)(wsb + fixed);
    unsigned short* hb   = volb + (size_t)n_lv * SN * NN * K1P2;

    // ---- weight prep + fmap conversion + vol K-pad zero ----
    conv_w1_kernel<<<dim3(K1P2 / 32, H1 / 32), 256, 0, stream>>>(w1, w1t);
    conv_t_kernel<<<dim3(H1 / 32, H2 / 32), 256, 0, stream>>>(w2, w2t, H1, H2, H1);
    for (int l = 0; l < 4; ++l)
        conv_fmap_kernel<<<SN * (Hs[l] + 8), 256, 0, stream>>>(
            fmaps[l], fpad[l], Hs[l], Ws[l]);
    zpad_kernel<<<(n_lv * SN * NN + 255) / 256, 256, 0, stream>>>(
        volb, n_lv * SN * NN);

    for (int lv0 = 0; lv0 < 4; lv0 += n_lv) {
        sample_vol_kernel<<<n_lv * NN, 256, 0, stream>>>(
            fpad[0], fpad[1], fpad[2], fpad[3],
            track[0], track[1], track[2], track[3],
            coords, volb, lv0);
        const int rows = n_lv * SN * NN;
        gemm1_kernel<<<(rows / 128) * 3, 256, 0, stream>>>(volb, w1t, b1, hb);
        gemm2_kernel<<<(rows / 128) * 2, 256, 0, stream>>>(hb, w2t, b2, te, out, lv0);
    }
    tail_kernel<<<SN * NN, 128, 0, stream>>>(coords, vis, conf, te, out);
}

// Round 16
// 337.935 us; speedup vs baseline: 1.1087x; 1.0161x over previous
//
#include <hip/hip_runtime.h>
#include <math.h>

// ---------------------------------------------------------------------------
// CoTracker correlation-embedding pipeline, bf16 MFMA, HWC-padded fmaps.
// Round 15: sample_vol MFMA operands swapped (trk as A, patch as B) so the
// pcL writeback is 5x ds_write_b64 per thread instead of 20x ds_write_u16.
// Everything else identical to R14 (2-deep patch pipe, permuted-K vol,
// distance-2 one-barrier gemms).
// Inputs: 0:fmaps0 1:track0 2:fmaps1 3:track1 4:fmaps2 5:track2 6:fmaps3
//         7:track3 8:coords 9:vis 10:conf 11:w1 12:b1 13:w2 14:b2 15:time_emb
// Output: (1,N,8,1110) f32.
// ---------------------------------------------------------------------------

#define SN 8
#define NN 1024
#define CC 128
#define K1P2 2752   // 343*8 = 2744 data + 8 pad (86 K-steps of 32)
#define H1 384
#define H2 256
#define DOUT 1110

typedef short bf16x8 __attribute__((ext_vector_type(8)));
typedef short s16x4 __attribute__((ext_vector_type(4)));
typedef float f32x4 __attribute__((ext_vector_type(4)));

__device__ inline unsigned short f2b(float x) {  // RTNE f32 -> bf16
    union { float f; unsigned u; } v; v.f = x;
    unsigned r = v.u + 0x7FFFu + ((v.u >> 16) & 1u);
    return (unsigned short)(r >> 16);
}
__device__ inline float b2f(unsigned short u) {
    union { unsigned u; float f; } v; v.u = (unsigned)u << 16; return v.f;
}
__device__ inline void gll16(const void* g, void* l) {
    __builtin_amdgcn_global_load_lds(
        (const __attribute__((address_space(1))) void*)g,
        (__attribute__((address_space(3))) void*)l, 16, 0, 0);
}
// XOR-swizzled LDS index (shorts) for [rows][128] bf16 MFMA operand tiles.
__device__ inline int swz(int row, int g) {
    return row * 128 + ((g ^ (row & 7)) << 3);
}

// ---------------------------------------------------------------------------
// fmap fp32 (S,C,H,W) -> bf16 HWC padded (S, H+8, W+8, C), border replicate.
// ---------------------------------------------------------------------------
__global__ __launch_bounds__(256) void conv_fmap_kernel(
    const float* __restrict__ in, unsigned short* __restrict__ outp,
    int H, int W)
{
    const int Hp = H + 8, Wp = W + 8;
    const int s = blockIdx.x / Hp, yp = blockIdx.x % Hp;
    const int y = min(max(yp - 4, 0), H - 1);
    const float* src = in + (size_t)s * CC * H * W + (size_t)y * W;
    unsigned short* dst = outp + ((size_t)s * Hp + yp) * Wp * CC;
    for (int idx = threadIdx.x; idx < Wp * CC; idx += 256) {
        int xp = idx >> 7, c = idx & 127;
        int x = min(max(xp - 4, 0), W - 1);
        dst[idx] = f2b(src[(size_t)c * H * W + x]);
    }
}

// ---------------------------------------------------------------------------
// Kernel A (fused over levels): block -> (g = blk>>10, n = blk&1023).
// 2-deep patch pipeline (bufB aliases trk after register-hoist). Per s:
// [counted vmcnt + bar] MFMA (trk as A) -> pcL via b64 writes
// [lgkm bar] issue patch(sl+2) -> bilinear (b64 taps) -> permuted-K vol.
// LDS 50.6KB -> 3 blocks/CU.
// ---------------------------------------------------------------------------
__global__ __launch_bounds__(256, 3) void sample_vol_kernel(
    const unsigned short* __restrict__ fq0, const unsigned short* __restrict__ fq1,
    const unsigned short* __restrict__ fq2, const unsigned short* __restrict__ fq3,
    const float* __restrict__ tk0, const float* __restrict__ tk1,
    const float* __restrict__ tk2, const float* __restrict__ tk3,
    const float* __restrict__ coords,        // (8, N, 2) f32
    unsigned short* __restrict__ vol,        // (n_lv*8*N, 2752) bf16 permuted-K
    int lv0)
{
    __shared__ __align__(16) unsigned short bufA[80 * 128]; // 20 KB
    __shared__ __align__(16) unsigned short bufB[80 * 128]; // 20 KB (trk alias)
    __shared__ __align__(16) unsigned short pcL[80 * 68];   // 10.6 KB
    const int n = blockIdx.x & 1023, g = blockIdx.x >> 10;
    const int lvl = lv0 + g;
    const unsigned short* fpad = (lvl == 0) ? fq0 : (lvl == 1) ? fq1
                               : (lvl == 2) ? fq2 : fq3;
    const float* track = (lvl == 0) ? tk0 : (lvl == 1) ? tk1
                       : (lvl == 2) ? tk2 : tk3;
    const int Wp = (128 >> lvl) + 8;
    const int t = threadIdx.x;
    const int lane = t & 63, wv = t >> 6;
    const int rsub = lane & 15, kq = lane >> 4;
    const float inv = 1.0f / (float)(1 << lvl);
    const size_t plane = (size_t)((96 >> lvl) + 8) * Wp * CC;

    int poff[5], ldso[5];
    #pragma unroll
    for (int i = 0; i < 5; ++i) {
        int task64 = wv * 5 + i;
        int point = task64 * 4 + (lane >> 4);  // patch row 0..79
        int v = point / 10, xs = point - v * 10;
        int j = (lane & 15) ^ (point & 7);
        poff[i] = (v * Wp + xs) * CC + j * 8;
        ldso[i] = task64 * 512;
    }

    float cxa[SN], cya[SN];
    int fxa[SN], fya[SN], ea[SN];
    #pragma unroll
    for (int s = 0; s < SN; ++s) {
        float2 c2 = *(const float2*)&coords[((size_t)s * NN + n) * 2];
        cxa[s] = c2.x * inv; cya[s] = c2.y * inv;
        fxa[s] = (int)floorf(cxa[s]);
        fya[s] = (int)floorf(cya[s]);
        ea[s] = (fxa[s] - 3) & ~1;
    }

    int p0b[2], ij0a[2], tau8[2]; bool vld[2];
    #pragma unroll
    for (int rep = 0; rep < 2; ++rep) {
        int tau = t + rep * 256;
        vld[rep] = (tau < 343);
        int tt = vld[rep] ? tau : 0;
        int ab = tt / 7, blk = tt - 7 * ab;
        int a = ab / 7, b = ab - 7 * a;
        p0b[rep] = b * 10 + a;
        ij0a[rep] = blk * 8;
        tau8[rep] = tt * 8;
    }

    // patch s=0 -> bufA
    {
        const unsigned short* base =
            fpad + ((fya[0] + 1) * Wp + (ea[0] + 4)) * CC;
        #pragma unroll
        for (int i = 0; i < 5; ++i) gll16(base + poff[i], &bufA[ldso[i]]);
    }
    // track[n] -> bufB (trk layout, swizzled), once
    for (int task = t; task < 49 * 16; task += 256) {
        int row = task >> 4, gg = task & 15;
        const float* srcp = &track[((size_t)row * NN + n) * CC + gg * 8];
        float4 f0 = *(const float4*)srcp;
        float4 f1 = *(const float4*)(srcp + 4);
        bf16x8 v8;
        v8[0] = f2b(f0.x); v8[1] = f2b(f0.y); v8[2] = f2b(f0.z); v8[3] = f2b(f0.w);
        v8[4] = f2b(f1.x); v8[5] = f2b(f1.y); v8[6] = f2b(f1.z); v8[7] = f2b(f1.w);
        *(bf16x8*)&bufB[swz(row, gg)] = v8;
    }
    {
        unsigned* T32 = (unsigned*)bufB;
        for (int i = t; i < 15 * 64; i += 256) T32[49 * 64 + i] = 0;
    }
    asm volatile("s_waitcnt lgkmcnt(0)" ::: "memory");
    __builtin_amdgcn_sched_barrier(0);
    __builtin_amdgcn_s_barrier();
    bf16x8 tf[4];
    #pragma unroll
    for (int kk = 0; kk < 4; ++kk)
        tf[kk] = *(const bf16x8*)&bufB[swz(wv * 16 + rsub, kk * 4 + kq)];
    asm volatile("s_waitcnt lgkmcnt(0)" ::: "memory");
    __builtin_amdgcn_sched_barrier(0);
    __builtin_amdgcn_s_barrier();
    __builtin_amdgcn_sched_barrier(0);
    // patch s=1 -> bufB (now free)
    {
        const unsigned short* base =
            fpad + plane + ((fya[1] + 1) * Wp + (ea[1] + 4)) * CC;
        #pragma unroll
        for (int i = 0; i < 5; ++i) gll16(base + poff[i], &bufB[ldso[i]]);
    }

    #pragma unroll
    for (int sl = 0; sl < SN; ++sl) {
        unsigned short* pbuf = (sl & 1) ? bufB : bufA;
        const float wx = cxa[sl] - (float)fxa[sl], wy = cya[sl] - (float)fya[sl];
        const float w00 = (1.f - wx) * (1.f - wy), w10 = wx * (1.f - wy);
        const float w01 = (1.f - wx) * wy,         w11 = wx * wy;
        const int off = fxa[sl] - 3 - ea[sl];

        if (sl == 0) {
            asm volatile("s_waitcnt vmcnt(5) lgkmcnt(0)" ::: "memory");
        } else if (sl == 1) {
            if (wv < 2) asm volatile("s_waitcnt vmcnt(7) lgkmcnt(0)" ::: "memory");
            else        asm volatile("s_waitcnt vmcnt(6) lgkmcnt(0)" ::: "memory");
        } else if (sl == SN - 1) {
            if (wv < 2) asm volatile("s_waitcnt vmcnt(4) lgkmcnt(0)" ::: "memory");
            else        asm volatile("s_waitcnt vmcnt(2) lgkmcnt(0)" ::: "memory");
        } else {
            if (wv < 2) asm volatile("s_waitcnt vmcnt(9) lgkmcnt(0)" ::: "memory");
            else        asm volatile("s_waitcnt vmcnt(7) lgkmcnt(0)" ::: "memory");
        }
        __builtin_amdgcn_sched_barrier(0);
        __builtin_amdgcn_s_barrier();
        __builtin_amdgcn_sched_barrier(0);

        // ---- MFMA (swapped): acc[ti] holds pc[p=ti*16+rsub][ij=wv*16+kq*4+r]
        // A = trk fragment (tf, register), B = patch fragment. A/B input
        // layouts are identical for 16x16x32, so fragments are unchanged;
        // only D's orientation flips -> b64 pcL writeback.
        {
            f32x4 acc[5] = {};
            __builtin_amdgcn_s_setprio(1);
            #pragma unroll
            for (int kk = 0; kk < 4; ++kk) {
                int gg = kk * 4 + kq;
                #pragma unroll
                for (int ti = 0; ti < 5; ++ti) {
                    bf16x8 b = *(const bf16x8*)&pbuf[swz(ti * 16 + rsub, gg)];
                    acc[ti] = __builtin_amdgcn_mfma_f32_16x16x32_bf16(tf[kk], b, acc[ti], 0, 0, 0);
                }
            }
            __builtin_amdgcn_s_setprio(0);
            const int ij0 = wv * 16 + kq * 4;   // 4 consecutive ij
            #pragma unroll
            for (int ti = 0; ti < 5; ++ti) {
                const int p = ti * 16 + rsub;
                s16x4 w4;
                w4[0] = (short)f2b(acc[ti][0]);
                w4[1] = (short)f2b(acc[ti][1]);
                w4[2] = (short)f2b(acc[ti][2]);
                w4[3] = (short)f2b(acc[ti][3]);
                *(s16x4*)&pcL[p * 68 + ij0] = w4;
            }
        }
        asm volatile("s_waitcnt lgkmcnt(0)" ::: "memory");
        __builtin_amdgcn_s_barrier();
        __builtin_amdgcn_sched_barrier(0);

        // ---- issue patch(sl+2) into the buffer just consumed ----
        if (sl + 2 < SN) {
            const unsigned short* base =
                fpad + (size_t)(sl + 2) * plane
                + ((fya[sl + 2] + 1) * Wp + (ea[sl + 2] + 4)) * CC;
            #pragma unroll
            for (int i = 0; i < 5; ++i) gll16(base + poff[i], &pbuf[ldso[i]]);
        }
        __builtin_amdgcn_sched_barrier(0);

        // ---- bilinear: per task 4 tap rows x 2 b64 reads -> 8 outputs ----
        {
            unsigned short* vrow = vol + ((size_t)(g * SN + sl) * NN + n) * K1P2;
            #pragma unroll
            for (int rep = 0; rep < 2; ++rep) {
                if (vld[rep]) {
                    int base = (p0b[rep] + off) * 68 + ij0a[rep];
                    s16x4 a0 = *(const s16x4*)&pcL[base],       a1 = *(const s16x4*)&pcL[base + 4];
                    s16x4 b0 = *(const s16x4*)&pcL[base + 68],  b1 = *(const s16x4*)&pcL[base + 72];
                    s16x4 c0 = *(const s16x4*)&pcL[base + 680], c1 = *(const s16x4*)&pcL[base + 684];
                    s16x4 d0 = *(const s16x4*)&pcL[base + 748], d1 = *(const s16x4*)&pcL[base + 752];
                    unsigned w[4];
                    #pragma unroll
                    for (int j = 0; j < 4; ++j) {
                        const int e0 = 2 * j, e1 = 2 * j + 1;
                        float v0 = w00 * b2f((unsigned short)(e0 < 4 ? a0[e0 & 3] : a1[e0 & 3]))
                                 + w10 * b2f((unsigned short)(e0 < 4 ? b0[e0 & 3] : b1[e0 & 3]))
                                 + w01 * b2f((unsigned short)(e0 < 4 ? c0[e0 & 3] : c1[e0 & 3]))
                                 + w11 * b2f((unsigned short)(e0 < 4 ? d0[e0 & 3] : d1[e0 & 3]));
                        float v1 = w00 * b2f((unsigned short)(e1 < 4 ? a0[e1 & 3] : a1[e1 & 3]))
                                 + w10 * b2f((unsigned short)(e1 < 4 ? b0[e1 & 3] : b1[e1 & 3]))
                                 + w01 * b2f((unsigned short)(e1 < 4 ? c0[e1 & 3] : c1[e1 & 3]))
                                 + w11 * b2f((unsigned short)(e1 < 4 ? d0[e1 & 3] : d1[e1 & 3]));
                        w[j] = (unsigned)f2b(v0) | ((unsigned)f2b(v1) << 16);
                    }
                    uint4 st; st.x = w[0]; st.y = w[1]; st.z = w[2]; st.w = w[3];
                    *(uint4*)(vrow + tau8[rep]) = st;
                }
            }
        }
    }
}

// ---------------------------------------------------------------------------
// Zero vol pad columns 2744..2751 (NaN shield for gemm1's K padding).
// ---------------------------------------------------------------------------
__global__ __launch_bounds__(256) void zpad_kernel(
    unsigned short* __restrict__ vol, int rows)
{
    int r = blockIdx.x * 256 + threadIdx.x;
    if (r < rows) {
        uint4 z; z.x = 0; z.y = 0; z.z = 0; z.w = 0;
        *(uint4*)(vol + (size_t)r * K1P2 + 2744) = z;
    }
}

// ---------------------------------------------------------------------------
// w1 (2401x384 f32) -> w1t (384x2752 bf16) with the bilinear K-permutation.
// ---------------------------------------------------------------------------
__global__ __launch_bounds__(256) void conv_w1_kernel(
    const float* __restrict__ w1, unsigned short* __restrict__ w1t)
{
    __shared__ float tile[32][33];
    const int kb = blockIdx.x * 32, nb = blockIdx.y * 32;
    const int tx = threadIdx.x & 31, ty = threadIdx.x >> 5;
    #pragma unroll
    for (int i = 0; i < 32; i += 8) {
        int kp = kb + ty + i;
        int k = -1;
        if (kp < 2744) {
            int tau = kp >> 3, r = kp & 7;
            int ab = tau / 7, blk = tau - 7 * ab;
            int ij = blk * 8 + r;
            if (ij < 49) k = ab * 49 + ij;
        }
        tile[ty + i][tx] = (k >= 0) ? w1[(size_t)k * H1 + nb + tx] : 0.f;
    }
    __syncthreads();
    #pragma unroll
    for (int i = 0; i < 32; i += 8)
        w1t[(size_t)(nb + ty + i) * K1P2 + kb + tx] = f2b(tile[tx][ty + i]);
}

// ---------------------------------------------------------------------------
// GEMM1: H = gelu(vol @ w1 + b1).  (rows x 2752) @ (2752 x 384) bf16.
// 3-buffer, prefetch distance 2, ONE barrier per K-step, vmcnt(4) steady.
// ---------------------------------------------------------------------------
__global__ __launch_bounds__(256, 3) void gemm1_kernel(
    const unsigned short* __restrict__ A,   // rows x 2752
    const unsigned short* __restrict__ Bt,  // 384 x 2752 (= w1^T permuted)
    const float* __restrict__ bias,
    unsigned short* __restrict__ Hout)      // rows x 384
{
    __shared__ __align__(16) unsigned short As[3 * 128 * 32];
    __shared__ __align__(16) unsigned short Bs[3 * 128 * 32];
    const int h = blockIdx.x, q = gridDim.x >> 3;
    const int l = (h & 7) * q + (h >> 3);
    const int m0 = (l / 3) * 128, n0 = (l % 3) * 128;
    const int t = threadIdx.x, lane = t & 63, wv = t >> 6;
    const int wm = wv >> 1, wn = wv & 1;
    const int rsub = lane & 15, kq = lane >> 4;

    const int rA0 = t >> 2, sA0 = (t & 3) ^ ((rA0 >> 1) & 3);
    const int rA1 = (t + 256) >> 2, sA1 = ((t + 256) & 3) ^ ((rA1 >> 1) & 3);
    const unsigned short* gA0 = A  + (size_t)(m0 + rA0) * K1P2 + sA0 * 8;
    const unsigned short* gA1 = A  + (size_t)(m0 + rA1) * K1P2 + sA1 * 8;
    const unsigned short* gB0 = Bt + (size_t)(n0 + rA0) * K1P2 + sA0 * 8;
    const unsigned short* gB1 = Bt + (size_t)(n0 + rA1) * K1P2 + sA1 * 8;
    const int chunk0 = (t & ~63) * 8, chunk1 = (256 + (t & ~63)) * 8;

    f32x4 acc[4][4] = {};

    const int NSTEP = K1P2 / 32;  // 86
    #pragma unroll
    for (int p = 0; p < 2; ++p) {  // prologue: tiles 0,1
        size_t ko = (size_t)p * 32;
        int lb = p * 4096;
        gll16(gA0 + ko, &As[lb + chunk0]); gll16(gA1 + ko, &As[lb + chunk1]);
        gll16(gB0 + ko, &Bs[lb + chunk0]); gll16(gB1 + ko, &Bs[lb + chunk1]);
    }
    int cur = 0, nxt = 2;
    for (int st = 0; st < NSTEP; ++st) {
        if (st + 1 < NSTEP) asm volatile("s_waitcnt vmcnt(4)" ::: "memory");
        else                asm volatile("s_waitcnt vmcnt(0)" ::: "memory");
        __builtin_amdgcn_s_barrier();
        __builtin_amdgcn_sched_barrier(0);
        if (st + 2 < NSTEP) {
            size_t ko = (size_t)(st + 2) * 32;
            int lb = nxt * 4096;
            gll16(gA0 + ko, &As[lb + chunk0]);
            gll16(gA1 + ko, &As[lb + chunk1]);
            gll16(gB0 + ko, &Bs[lb + chunk0]);
            gll16(gB1 + ko, &Bs[lb + chunk1]);
        }
        const int lb = cur * 4096;
        bf16x8 af[4], bfr[4];
        #pragma unroll
        for (int mi = 0; mi < 4; ++mi) {
            int r = wm * 64 + mi * 16 + rsub;
            int phys = r * 4 + (kq ^ ((r >> 1) & 3));
            af[mi] = *(const bf16x8*)&As[lb + phys * 8];
        }
        #pragma unroll
        for (int ni = 0; ni < 4; ++ni) {
            int r = wn * 64 + ni * 16 + rsub;
            int phys = r * 4 + (kq ^ ((r >> 1) & 3));
            bfr[ni] = *(const bf16x8*)&Bs[lb + phys * 8];
        }
        __builtin_amdgcn_s_setprio(1);
        #pragma unroll
        for (int mi = 0; mi < 4; ++mi)
            #pragma unroll
            for (int ni = 0; ni < 4; ++ni)
                acc[mi][ni] = __builtin_amdgcn_mfma_f32_16x16x32_bf16(
                    af[mi], bfr[ni], acc[mi][ni], 0, 0, 0);
        __builtin_amdgcn_s_setprio(0);
        cur = (cur == 2) ? 0 : cur + 1;
        nxt = (nxt == 2) ? 0 : nxt + 1;
    }
    #pragma unroll
    for (int mi = 0; mi < 4; ++mi) {
        int row = m0 + wm * 64 + mi * 16 + kq * 4;
        #pragma unroll
        for (int ni = 0; ni < 4; ++ni) {
            int col = n0 + wn * 64 + ni * 16 + rsub;
            float bcol = bias[col];
            #pragma unroll
            for (int r = 0; r < 4; ++r) {
                float x = acc[mi][ni][r] + bcol;
                float gg = 0.5f * x * (1.f + erff(x * 0.70710678118654752f));
                Hout[(size_t)(row + r) * H1 + col] = f2b(gg);
            }
        }
    }
}

// ---------------------------------------------------------------------------
// GEMM2: out slice = H @ w2 + b2 + time_emb.  (rows x 384) @ (384 x 256).
// Same distance-2 one-barrier scheme.
// ---------------------------------------------------------------------------
__global__ __launch_bounds__(256, 3) void gemm2_kernel(
    const unsigned short* __restrict__ A,   // rows x 384
    const unsigned short* __restrict__ Bt,  // 256 x 384 (= w2^T)
    const float* __restrict__ bias,
    const float* __restrict__ te,           // (8, 1110)
    float* __restrict__ out,                // (N, 8, 1110)
    int lv0)
{
    __shared__ __align__(16) unsigned short As[3 * 128 * 32];
    __shared__ __align__(16) unsigned short Bs[3 * 128 * 32];
    const int h = blockIdx.x, q = gridDim.x >> 3;
    const int l = (h & 7) * q + (h >> 3);
    const int m0 = (l >> 1) * 128, n0 = (l & 1) * 128;
    const int t = threadIdx.x, lane = t & 63, wv = t >> 6;
    const int wm = wv >> 1, wn = wv & 1;
    const int rsub = lane & 15, kq = lane >> 4;

    const int rA0 = t >> 2, sA0 = (t & 3) ^ ((rA0 >> 1) & 3);
    const int rA1 = (t + 256) >> 2, sA1 = ((t + 256) & 3) ^ ((rA1 >> 1) & 3);
    const unsigned short* gA0 = A  + (size_t)(m0 + rA0) * H1 + sA0 * 8;
    const unsigned short* gA1 = A  + (size_t)(m0 + rA1) * H1 + sA1 * 8;
    const unsigned short* gB0 = Bt + (size_t)(n0 + rA0) * H1 + sA0 * 8;
    const unsigned short* gB1 = Bt + (size_t)(n0 + rA1) * H1 + sA1 * 8;
    const int chunk0 = (t & ~63) * 8, chunk1 = (256 + (t & ~63)) * 8;

    f32x4 acc[4][4] = {};

    const int NSTEP = H1 / 32;  // 12
    #pragma unroll
    for (int p = 0; p < 2; ++p) {
        size_t ko = (size_t)p * 32;
        int lb = p * 4096;
        gll16(gA0 + ko, &As[lb + chunk0]); gll16(gA1 + ko, &As[lb + chunk1]);
        gll16(gB0 + ko, &Bs[lb + chunk0]); gll16(gB1 + ko, &Bs[lb + chunk1]);
    }
    int cur = 0, nxt = 2;
    for (int st = 0; st < NSTEP; ++st) {
        if (st + 1 < NSTEP) asm volatile("s_waitcnt vmcnt(4)" ::: "memory");
        else                asm volatile("s_waitcnt vmcnt(0)" ::: "memory");
        __builtin_amdgcn_s_barrier();
        __builtin_amdgcn_sched_barrier(0);
        if (st + 2 < NSTEP) {
            size_t ko = (size_t)(st + 2) * 32;
            int lb = nxt * 4096;
            gll16(gA0 + ko, &As[lb + chunk0]);
            gll16(gA1 + ko, &As[lb + chunk1]);
            gll16(gB0 + ko, &Bs[lb + chunk0]);
            gll16(gB1 + ko, &Bs[lb + chunk1]);
        }
        const int lb = cur * 4096;
        bf16x8 af[4], bfr[4];
        #pragma unroll
        for (int mi = 0; mi < 4; ++mi) {
            int r = wm * 64 + mi * 16 + rsub;
            int phys = r * 4 + (kq ^ ((r >> 1) & 3));
            af[mi] = *(const bf16x8*)&As[lb + phys * 8];
        }
        #pragma unroll
        for (int ni = 0; ni < 4; ++ni) {
            int r = wn * 64 + ni * 16 + rsub;
            int phys = r * 4 + (kq ^ ((r >> 1) & 3));
            bfr[ni] = *(const bf16x8*)&Bs[lb + phys * 8];
        }
        __builtin_amdgcn_s_setprio(1);
        #pragma unroll
        for (int mi = 0; mi < 4; ++mi)
            #pragma unroll
            for (int ni = 0; ni < 4; ++ni)
                acc[mi][ni] = __builtin_amdgcn_mfma_f32_16x16x32_bf16(
                    af[mi], bfr[ni], acc[mi][ni], 0, 0, 0);
        __builtin_amdgcn_s_setprio(0);
        cur = (cur == 2) ? 0 : cur + 1;
        nxt = (nxt == 2) ? 0 : nxt + 1;
    }
    #pragma unroll
    for (int mi = 0; mi < 4; ++mi) {
        int rowb = m0 + wm * 64 + mi * 16 + kq * 4;
        #pragma unroll
        for (int ni = 0; ni < 4; ++ni) {
            int col = n0 + wn * 64 + ni * 16 + rsub;
            float bcol = bias[col];
            #pragma unroll
            for (int r = 0; r < 4; ++r) {
                int row = rowb + r;
                int g = row >> 13, s = (row >> 10) & 7, n = row & 1023;
                int dcol = 2 + (lv0 + g) * H2 + col;
                out[((size_t)n * SN + s) * DOUT + dcol] =
                    acc[mi][ni][r] + bcol + te[s * DOUT + dcol];
            }
        }
    }
}

// ---------------------------------------------------------------------------
// Transpose + bf16-convert: in (K x Nw f32) -> out (Nw x Kp bf16), zero-pad.
// ---------------------------------------------------------------------------
__global__ __launch_bounds__(256) void conv_t_kernel(
    const float* __restrict__ in, unsigned short* __restrict__ outp,
    int K, int Nw, int Kp)
{
    __shared__ float tile[32][33];
    const int kb = blockIdx.x * 32, nb = blockIdx.y * 32;
    const int tx = threadIdx.x & 31, ty = threadIdx.x >> 5;
    #pragma unroll
    for (int i = 0; i < 32; i += 8) {
        int k = kb + ty + i, nn = nb + tx;
        tile[ty + i][tx] = (k < K && nn < Nw) ? in[(size_t)k * Nw + nn] : 0.f;
    }
    __syncthreads();
    #pragma unroll
    for (int i = 0; i < 32; i += 8) {
        int nn = nb + ty + i, k = kb + tx;
        if (nn < Nw) outp[(size_t)nn * Kp + k] = f2b(tile[tx][ty + i]);
    }
}

// Kernel D: vis, conf, rel_emb(84) + time_emb.
__global__ __launch_bounds__(128) void tail_kernel(
    const float* __restrict__ coords, const float* __restrict__ vis,
    const float* __restrict__ conf, const float* __restrict__ te,
    float* __restrict__ out)
{
    const int b = blockIdx.x;
    const int n = b >> 3, s = b & 7;
    const int d = threadIdx.x;
    if (d >= 86) return;
    const size_t ob = (size_t)b * DOUT;
    if (d == 0) {
        out[ob + 0] = vis[(size_t)s * NN + n] + te[s * DOUT + 0];
    } else if (d == 1) {
        out[ob + 1] = conf[(size_t)s * NN + n] + te[s * DOUT + 1];
    } else {
        int rd = d - 2;
        float cx = coords[((size_t)s * NN + n) * 2 + 0];
        float cy = coords[((size_t)s * NN + n) * 2 + 1];
        float rfx = 0.f, rfy = 0.f, rbx = 0.f, rby = 0.f;
        if (s < SN - 1) {
            rfx = cx - coords[((size_t)(s + 1) * NN + n) * 2 + 0];
            rfy = cy - coords[((size_t)(s + 1) * NN + n) * 2 + 1];
        }
        if (s > 0) {
            rbx = cx - coords[((size_t)(s - 1) * NN + n) * 2 + 0];
            rby = cy - coords[((size_t)(s - 1) * NN + n) * 2 + 1];
        }
        float r4[4] = {rfx / 128.f, rfy / 96.f, rbx / 128.f, rby / 96.f};
        float val;
        if (rd < 4) {
            val = r4[rd];
        } else if (rd < 44) {
            int q = rd - 4; int deg = q >> 2, comp = q & 3;
            val = sinf(r4[comp] * (float)(1 << deg));
        } else {
            int q = rd - 44; int deg = q >> 2, comp = q & 3;
            val = sinf(r4[comp] * (float)(1 << deg) + 1.57079632679489662f);
        }
        int od = 1026 + rd;
        out[ob + od] = val + te[s * DOUT + od];
    }
}

extern "C" void kernel_launch(void* const* d_in, const int* in_sizes, int n_in,
                              void* d_out, int out_size, void* d_ws, size_t ws_size,
                              hipStream_t stream) {
    const float* fmaps[4] = {(const float*)d_in[0], (const float*)d_in[2],
                             (const float*)d_in[4], (const float*)d_in[6]};
    const float* track[4] = {(const float*)d_in[1], (const float*)d_in[3],
                             (const float*)d_in[5], (const float*)d_in[7]};
    const float* coords = (const float*)d_in[8];
    const float* vis    = (const float*)d_in[9];
    const float* conf   = (const float*)d_in[10];
    const float* w1     = (const float*)d_in[11];
    const float* b1     = (const float*)d_in[12];
    const float* w2     = (const float*)d_in[13];
    const float* b2     = (const float*)d_in[14];
    const float* te     = (const float*)d_in[15];
    float* out = (float*)d_out;

    const int Hs[4] = {96, 48, 24, 12};
    const int Ws[4] = {128, 64, 32, 16};

    // ---- workspace layout ----
    char* wsb = (char*)d_ws;
    unsigned short* w1t = (unsigned short*)wsb;
    size_t off = (size_t)H1 * K1P2 * 2;
    unsigned short* w2t = (unsigned short*)(wsb + off);
    off += (size_t)H2 * H1 * 2;
    unsigned short* fpad[4];
    for (int l = 0; l < 4; ++l) {
        fpad[l] = (unsigned short*)(wsb + off);
        off += (size_t)SN * (Hs[l] + 8) * (Ws[l] + 8) * CC * 2;
    }
    off += 512;  // slack
    const size_t fixed = off;
    int n_lv = 4;
    while (n_lv > 1 &&
           fixed + (size_t)n_lv * SN * NN * (K1P2 + H1) * 2 > ws_size)
        n_lv >>= 1;
    unsigned short* volb = (unsigned short*)(wsb + fixed);
    unsigned short* hb   = volb + (size_t)n_lv * SN * NN * K1P2;

    // ---- weight prep + fmap conversion + vol K-pad zero ----
    conv_w1_kernel<<<dim3(K1P2 / 32, H1 / 32), 256, 0, stream>>>(w1, w1t);
    conv_t_kernel<<<dim3(H1 / 32, H2 / 32), 256, 0, stream>>>(w2, w2t, H1, H2, H1);
    for (int l = 0; l < 4; ++l)
        conv_fmap_kernel<<<SN * (Hs[l] + 8), 256, 0, stream>>>(
            fmaps[l], fpad[l], Hs[l], Ws[l]);
    zpad_kernel<<<(n_lv * SN * NN + 255) / 256, 256, 0, stream>>>(
        volb, n_lv * SN * NN);

    for (int lv0 = 0; lv0 < 4; lv0 += n_lv) {
        sample_vol_kernel<<<n_lv * NN, 256, 0, stream>>>(
            fpad[0], fpad[1], fpad[2], fpad[3],
            track[0], track[1], track[2], track[3],
            coords, volb, lv0);
        const int rows = n_lv * SN * NN;
        gemm1_kernel<<<(rows / 128) * 3, 256, 0, stream>>>(volb, w1t, b1, hb);
        gemm2_kernel<<<(rows / 128) * 2, 256, 0, stream>>>(hb, w2t, b2, te, out, lv0);
    }
    tail_kernel<<<SN * NN, 128, 0, stream>>>(coords, vis, conf, te, out);
}